// Round 16
// baseline (160.977 us; speedup 1.0000x reference)
//
#include <hip/hip_runtime.h>
#include <math.h>

#define NR 8192
#define N_OSC 28
#define TWO_PI_F 6.28318530717958647692f
#define PLANE 524288   // 8192 rows * 64 k, ushorts, per plane

typedef __attribute__((ext_vector_type(8))) short s16x8;
typedef __attribute__((ext_vector_type(16))) float f32x16;
typedef __attribute__((ext_vector_type(4))) float f32x4;
typedef __attribute__((ext_vector_type(4))) unsigned int u32x4;

#define AS3(p) ((__attribute__((address_space(3))) void*)(p))
#define AS1C(p) ((const __attribute__((address_space(1))) void*)(p))

__device__ __forceinline__ float modpos(float x) {
    float r = fmodf(x, TWO_PI_F);
    if (r < 0.0f) r += TWO_PI_F;
    return r;
}
__device__ __forceinline__ unsigned fmono(float f) {
    unsigned u = __float_as_uint(f);
    return (u & 0x80000000u) ? ~u : (u | 0x80000000u);
}
__device__ __forceinline__ unsigned short f2bf(float f) {  // RNE f32->bf16 bits
    unsigned u = __float_as_uint(f);
    return (unsigned short)((u + 0x7FFFu + ((u >> 16) & 1u)) >> 16);
}
__device__ __forceinline__ float bf2f(unsigned short h) {
    return __uint_as_float(((unsigned)h) << 16);
}

// Fragment-major table layout: element (row, k) ->
//   (row>>5)*2048 + (k>>4)*512 + ((k>>3)&1)*256 + (row&31)*8 + (k&7)
// A wave's (group, ks) fragment is 1KB contiguous: base + lane*8 ushorts.
// Values PRE-SCALED by 1/norm so MFMA output is the final sim value.

// -------- phase encode + advance + norm-scaled bf16 hi/mid/lo planes --------
__global__ __launch_bounds__(128) void encode_kernel(
    const float* __restrict__ detA, const float* __restrict__ detB,
    const float* __restrict__ W1, const float* __restrict__ b1,
    const float* __restrict__ W2, const float* __restrict__ b2,
    const float* __restrict__ freq,
    unsigned short* __restrict__ tabA, unsigned short* __restrict__ tabB,
    unsigned long long* __restrict__ rowMax, unsigned long long* __restrict__ colWin)
{
    __shared__ float sW1[4 * 64];
    __shared__ float sb1[64];
    __shared__ float sW2[64 * N_OSC];
    __shared__ float sb2[N_OSC];
    __shared__ float sDelta[N_OSC];

    int t = threadIdx.x;
    for (int i = t; i < 4 * 64; i += 128) sW1[i] = W1[i];
    for (int i = t; i < 64; i += 128) sb1[i] = b1[i];
    for (int i = t; i < 64 * N_OSC; i += 128) sW2[i] = W2[i];
    for (int i = t; i < N_OSC; i += 128) {
        sb2[i] = b2[i];
        sDelta[i] = (TWO_PI_F * freq[i]) * 0.01f;
    }
    __syncthreads();

    int gid = blockIdx.x * 128 + t;      // 16384 total
    bool isA = gid < NR;
    int row = isA ? gid : gid - NR;
    const float* det = isA ? detA : detB;
    unsigned short* tab = isA ? tabA : tabB;

    // fold the two tiny memsets into this kernel
    if (isA) rowMax[gid] = 0ull; else colWin[gid - NR] = 0ull;

    float4 xv = *(const float4*)(det + (size_t)row * 4);
    float x0 = xv.x, x1 = xv.y, x2 = xv.z, x3 = xv.w;

    float h[64];
#pragma unroll
    for (int j = 0; j < 64; ++j) {
        float a = x0 * sW1[0 * 64 + j];
        a += x1 * sW1[1 * 64 + j];
        a += x2 * sW1[2 * 64 + j];
        a += x3 * sW1[3 * 64 + j];
        a += sb1[j];
        h[j] = fmaxf(a, 0.0f);
    }

    float raw[N_OSC];
#pragma unroll
    for (int o = 0; o < N_OSC; ++o) raw[o] = 0.0f;
#pragma unroll
    for (int j = 0; j < 64; ++j) {
        float hj = h[j];
#pragma unroll
        for (int o = 0; o < N_OSC; ++o) raw[o] += hj * sW2[j * N_OSC + o];
    }

    float cv[N_OSC], sv[N_OSC];
    float csum = 0.0f;
#pragma unroll
    for (int o = 0; o < N_OSC; ++o) {
        float p = raw[o] + sb2[o];
        p = modpos(p);
        if (isA) {
            float d = sDelta[o];
#pragma unroll
            for (int s = 0; s < 5; ++s) { p = modpos(p + d); }
        }
        float sn, cs;
        sincosf(p, &sn, &cs);
        cv[o] = cs; sv[o] = sn;
        csum += cs * cs + sn * sn;
    }
    float irn = 1.0f / (sqrtf(csum) + 1e-6f);

    unsigned h2[32], m2[32], l2[32];
#pragma unroll
    for (int i = 0; i < 32; ++i) { h2[i] = 0u; m2[i] = 0u; l2[i] = 0u; }

#pragma unroll
    for (int o = 0; o < N_OSC; ++o) {
        {   // k = o (cos, scaled)
            float x = cv[o] * irn;
            unsigned short v0 = f2bf(x); float r1 = x - bf2f(v0);
            unsigned short v1 = f2bf(r1); float r2 = r1 - bf2f(v1);
            unsigned short v2 = f2bf(r2);
            const int k = o, i = k >> 1, sh = (k & 1) * 16;
            h2[i] |= ((unsigned)v0) << sh;
            m2[i] |= ((unsigned)v1) << sh;
            l2[i] |= ((unsigned)v2) << sh;
        }
        {   // k = 28 + o (sin, scaled)
            float x = sv[o] * irn;
            unsigned short v0 = f2bf(x); float r1 = x - bf2f(v0);
            unsigned short v1 = f2bf(r1); float r2 = r1 - bf2f(v1);
            unsigned short v2 = f2bf(r2);
            const int k = 28 + o, i = k >> 1, sh = (k & 1) * 16;
            h2[i] |= ((unsigned)v0) << sh;
            m2[i] |= ((unsigned)v1) << sh;
            l2[i] |= ((unsigned)v2) << sh;
        }
    }

    size_t gbase = (size_t)(row >> 5) * 2048 + (size_t)(row & 31) * 8;
#pragma unroll
    for (int c = 0; c < 8; ++c) {
        size_t off = gbase + (size_t)(c >> 1) * 512 + (size_t)(c & 1) * 256;
        u32x4 vh, vm, vl;
#pragma unroll
        for (int e = 0; e < 4; ++e) {
            vh[e] = h2[c * 4 + e]; vm[e] = m2[c * 4 + e]; vl[e] = l2[c * 4 + e];
        }
        *(u32x4*)(tab + off) = vh;
        *(u32x4*)(tab + PLANE + off) = vm;
        *(u32x4*)(tab + 2 * PLANE + off) = vl;
    }
}

#define MFMA(a, b, c) __builtin_amdgcn_mfma_f32_32x32x16_bf16((a), (b), (c), 0, 0, 0)

// -------- sim: 128x128 tile, 4-wave quadrants, all-LDS conflict-free staging,
//          swapped-operand MFMA, in-register row-max, b128 scratch epilogue --------
__global__ __launch_bounds__(256) void sim_kernel(
    const unsigned short* __restrict__ tabA, const unsigned short* __restrict__ tabB,
    float* __restrict__ simOut, unsigned long long* __restrict__ rowMax)
{
    __shared__ __align__(16) unsigned char smem[81920];
    // [0,49152): B 3 planes x 4 groups x 4 ks x 1KB
    // [49152, 81920): A double buffer, 2 x (4 groups x 4 ks x 1KB)
    // epilogue: reused as 4 x 16640B wave-private scratch

    int bid = blockIdx.x;
    int swz = (bid & 7) * 512 + (bid >> 3);    // 4096 blocks, bijective XCD swizzle
    int bx = swz & 63, by = swz >> 6;
    int r0 = by * 128, c0 = bx * 128;

    int t = threadIdx.x, w = t >> 6, l = t & 63;
    int wr = w >> 1, wc = w & 1;
    int l31 = l & 31, h5 = l >> 5;
    int gA0 = r0 >> 5, gB0 = c0 >> 5;
    size_t l8 = (size_t)l * 8;

    // ---- stage B (48 units) + A_hi (16 units) ----
#pragma unroll
    for (int i = 0; i < 12; ++i) {
        int unit = w * 12 + i;
        int p = unit >> 4, rem = unit & 15;
        int g = rem >> 2, ks = rem & 3;
        const unsigned short* src = tabB + (size_t)p * PLANE
            + (size_t)(gB0 + g) * 2048 + (size_t)ks * 512 + l8;
        __builtin_amdgcn_global_load_lds(AS1C(src), AS3(smem + unit * 1024), 16, 0, 0);
    }
#pragma unroll
    for (int i = 0; i < 4; ++i) {
        int unit = w * 4 + i;
        int g = unit >> 2, ks = unit & 3;
        const unsigned short* src = tabA
            + (size_t)(gA0 + g) * 2048 + (size_t)ks * 512 + l8;
        __builtin_amdgcn_global_load_lds(AS1C(src), AS3(smem + 49152 + unit * 1024), 16, 0, 0);
    }
    __builtin_amdgcn_sched_barrier(0);
    __syncthreads();

    // issue A_mid into buf1 (fresh region, lands by next barrier)
#pragma unroll
    for (int i = 0; i < 4; ++i) {
        int unit = w * 4 + i;
        int g = unit >> 2, ks = unit & 3;
        const unsigned short* src = tabA + PLANE
            + (size_t)(gA0 + g) * 2048 + (size_t)ks * 512 + l8;
        __builtin_amdgcn_global_load_lds(AS1C(src), AS3(smem + 65536 + unit * 1024), 16, 0, 0);
    }
    __builtin_amdgcn_sched_barrier(0);

    f32x16 acc00, acc01, acc10, acc11;   // acc[ag][bg]
#pragma unroll
    for (int r = 0; r < 16; ++r) { acc00[r] = 0.f; acc01[r] = 0.f; acc10[r] = 0.f; acc11[r] = 0.f; }

#define LDB(p, gg, ks) (*(const s16x8*)(smem + (((p) * 16 + (2 * wc + (gg)) * 4 + (ks)) * 1024) + (size_t)l * 16))
#define LDA(buf, gg, ks) (*(const s16x8*)(smem + 49152 + (buf) * 16384 + (((2 * wr + (gg)) * 4 + (ks)) * 1024) + (size_t)l * 16))

    s16x8 bh0[4], bh1[4];    // B_hi cached across phases (32 VGPR)

    // phase 0: A_hi x {B_hi, B_mid, B_lo}
#pragma unroll
    for (int ks = 0; ks < 4; ++ks) {
        s16x8 ah0 = LDA(0, 0, ks), ah1 = LDA(0, 1, ks);
        bh0[ks] = LDB(0, 0, ks); bh1[ks] = LDB(0, 1, ks);
        s16x8 q0 = LDB(1, 0, ks), q1 = LDB(1, 1, ks);
        s16x8 p0 = LDB(2, 0, ks), p1 = LDB(2, 1, ks);
        acc00 = MFMA(bh0[ks], ah0, acc00); acc01 = MFMA(bh1[ks], ah0, acc01);   // hh
        acc10 = MFMA(bh0[ks], ah1, acc10); acc11 = MFMA(bh1[ks], ah1, acc11);
        acc00 = MFMA(q0, ah0, acc00); acc01 = MFMA(q1, ah0, acc01);             // hm
        acc10 = MFMA(q0, ah1, acc10); acc11 = MFMA(q1, ah1, acc11);
        acc00 = MFMA(p0, ah0, acc00); acc01 = MFMA(p1, ah0, acc01);             // hl
        acc10 = MFMA(p0, ah1, acc10); acc11 = MFMA(p1, ah1, acc11);
    }
    __syncthreads();

    // issue A_lo into buf0 (A_hi fully consumed)
#pragma unroll
    for (int i = 0; i < 4; ++i) {
        int unit = w * 4 + i;
        int g = unit >> 2, ks = unit & 3;
        const unsigned short* src = tabA + 2 * PLANE
            + (size_t)(gA0 + g) * 2048 + (size_t)ks * 512 + l8;
        __builtin_amdgcn_global_load_lds(AS1C(src), AS3(smem + 49152 + unit * 1024), 16, 0, 0);
    }
    __builtin_amdgcn_sched_barrier(0);

    // phase 1: A_mid x {B_hi(regs), B_mid}
#pragma unroll
    for (int ks = 0; ks < 4; ++ks) {
        s16x8 am0 = LDA(1, 0, ks), am1 = LDA(1, 1, ks);
        s16x8 q0 = LDB(1, 0, ks), q1 = LDB(1, 1, ks);
        acc00 = MFMA(bh0[ks], am0, acc00); acc01 = MFMA(bh1[ks], am0, acc01);   // mh
        acc10 = MFMA(bh0[ks], am1, acc10); acc11 = MFMA(bh1[ks], am1, acc11);
        acc00 = MFMA(q0, am0, acc00); acc01 = MFMA(q1, am0, acc01);             // mm
        acc10 = MFMA(q0, am1, acc10); acc11 = MFMA(q1, am1, acc11);
    }
    __syncthreads();

    // phase 2: A_lo x B_hi(regs)
#pragma unroll
    for (int ks = 0; ks < 4; ++ks) {
        s16x8 al0 = LDA(0, 0, ks), al1 = LDA(0, 1, ks);
        acc00 = MFMA(bh0[ks], al0, acc00); acc01 = MFMA(bh1[ks], al0, acc01);   // lh
        acc10 = MFMA(bh0[ks], al1, acc10); acc11 = MFMA(bh1[ks], al1, acc11);
    }
#undef LDA
#undef LDB

    // ---- in-register row max/argmax (rows lane-local via swapped operands) ----
    int cbase = c0 + wc * 64 + 4 * h5;
    unsigned long long key0 = 0ull, key1 = 0ull;
#pragma unroll
    for (int r = 0; r < 16; ++r) {
        int pa = (r & 3) + 8 * (r >> 2);
        unsigned col0 = (unsigned)(cbase + pa);
        unsigned col1 = (unsigned)(cbase + 32 + pa);
        unsigned long long k;
        k = ((unsigned long long)fmono(acc00[r]) << 32) | (unsigned long long)(0xFFFFFFFFu - col0);
        if (k > key0) key0 = k;
        k = ((unsigned long long)fmono(acc01[r]) << 32) | (unsigned long long)(0xFFFFFFFFu - col1);
        if (k > key0) key0 = k;
        k = ((unsigned long long)fmono(acc10[r]) << 32) | (unsigned long long)(0xFFFFFFFFu - col0);
        if (k > key1) key1 = k;
        k = ((unsigned long long)fmono(acc11[r]) << 32) | (unsigned long long)(0xFFFFFFFFu - col1);
        if (k > key1) key1 = k;
    }
    {   // merge lane l <-> l+32 (same rows, complementary col subsets)
        unsigned lo = (unsigned)key0, hi = (unsigned)(key0 >> 32);
        unsigned olo = __shfl_xor(lo, 32, 64), ohi = __shfl_xor(hi, 32, 64);
        unsigned long long o = ((unsigned long long)ohi << 32) | olo;
        if (o > key0) key0 = o;
        lo = (unsigned)key1; hi = (unsigned)(key1 >> 32);
        olo = __shfl_xor(lo, 32, 64); ohi = __shfl_xor(hi, 32, 64);
        o = ((unsigned long long)ohi << 32) | olo;
        if (o > key1) key1 = o;
    }
    if (l < 32) {
        atomicMax(&rowMax[r0 + wr * 64 + l], key0);
        atomicMax(&rowMax[r0 + wr * 64 + 32 + l], key1);
    }

    // ---- store via wave-private LDS transpose scratch (b128 both ways) ----
    __syncthreads();                          // all LDS reads done; reuse smem
    float* scr = (float*)(smem + w * 16640);  // 64 rows x pitch 65 floats

#pragma unroll
    for (int ag = 0; ag < 2; ++ag) {
#pragma unroll
        for (int bg = 0; bg < 2; ++bg) {
#pragma unroll
            for (int k = 0; k < 4; ++k) {
                f32x4 v;
#pragma unroll
                for (int e = 0; e < 4; ++e) {
                    float x = ag == 0 ? (bg == 0 ? acc00[4 * k + e] : acc01[4 * k + e])
                                      : (bg == 0 ? acc10[4 * k + e] : acc11[4 * k + e]);
                    v[e] = x;
                }
                int rrow = ag * 32 + l31;
                int ccol = bg * 32 + 8 * k + 4 * h5;
                *(f32x4*)&scr[rrow * 65 + ccol] = v;
            }
        }
    }
    // wave-private: no barrier between write and read

#pragma unroll
    for (int s = 0; s < 16; ++s) {
        int lr = 4 * s + (l >> 4);
        f32x4 v = *(const f32x4*)&scr[lr * 65 + (l & 15) * 4];
        __builtin_nontemporal_store(v,
            (f32x4*)&simOut[(size_t)(r0 + wr * 64 + lr) * NR + c0 + wc * 64 + (l & 15) * 4]);
    }
}

// -------- per-row: init matches, claim column --------
__global__ __launch_bounds__(256) void rowwin_kernel(
    const unsigned long long* __restrict__ rowMax,
    unsigned long long* __restrict__ colWin,
    float* __restrict__ outMatches)
{
    int r = blockIdx.x * 256 + threadIdx.x;
    if (r >= NR) return;
    outMatches[r] = -1.0f;
    unsigned long long key = rowMax[r];
    unsigned m = (unsigned)(key >> 32);
    unsigned bits = (m & 0x80000000u) ? (m ^ 0x80000000u) : ~m;
    float ms = __uint_as_float(bits);
    unsigned col = 0xFFFFFFFFu - (unsigned)key;
    if (ms > 0.3f) {
        unsigned long long ck = ((unsigned long long)m << 32)
                              | (unsigned long long)(0xFFFFFFFFu - (unsigned)r);
        atomicMax(&colWin[col], ck);
    }
}

// -------- per-column: winner takes the column --------
__global__ __launch_bounds__(256) void colfin_kernel(
    const unsigned long long* __restrict__ colWin,
    float* __restrict__ outMatches)
{
    int j = blockIdx.x * 256 + threadIdx.x;
    if (j >= NR) return;
    unsigned long long w = colWin[j];
    if (w != 0ull) {
        unsigned r = 0xFFFFFFFFu - (unsigned)w;
        outMatches[r] = (float)j;
    }
}

extern "C" void kernel_launch(void* const* d_in, const int* in_sizes, int n_in,
                              void* d_out, int out_size, void* d_ws, size_t ws_size,
                              hipStream_t stream) {
    const float* detA = (const float*)d_in[0];
    const float* detB = (const float*)d_in[1];
    const float* W1   = (const float*)d_in[2];
    const float* b1   = (const float*)d_in[3];
    const float* W2   = (const float*)d_in[4];
    const float* b2   = (const float*)d_in[5];
    const float* freq = (const float*)d_in[6];
    float* out = (float*)d_out;

    char* ws = (char*)d_ws;
    unsigned short* tabA = (unsigned short*)(ws);             // 3 planes x 1 MB
    unsigned short* tabB = (unsigned short*)(ws + 3145728);   // 3 planes x 1 MB
    unsigned long long* rowMax = (unsigned long long*)(ws + 6291456); // 64 KB
    unsigned long long* colWin = (unsigned long long*)(ws + 6356992); // 64 KB

    encode_kernel<<<128, 128, 0, stream>>>(detA, detB, W1, b1, W2, b2, freq,
                                           tabA, tabB, rowMax, colWin);
    sim_kernel<<<4096, 256, 0, stream>>>(tabA, tabB, out + NR, rowMax);
    rowwin_kernel<<<NR / 256, 256, 0, stream>>>(rowMax, colWin, out);
    colfin_kernel<<<NR / 256, 256, 0, stream>>>(colWin, out);
}

// Round 17
// 159.710 us; speedup vs baseline: 1.0079x; 1.0079x over previous
//
#include <hip/hip_runtime.h>
#include <math.h>

#define NR 8192
#define N_OSC 28
#define TWO_PI_F 6.28318530717958647692f
#define PLANE 524288   // 8192 rows * 64 k, ushorts, per plane

typedef __attribute__((ext_vector_type(8))) short s16x8;
typedef __attribute__((ext_vector_type(16))) float f32x16;
typedef __attribute__((ext_vector_type(4))) float f32x4;
typedef __attribute__((ext_vector_type(4))) unsigned int u32x4;

#define AS3(p) ((__attribute__((address_space(3))) void*)(p))
#define AS1C(p) ((const __attribute__((address_space(1))) void*)(p))

__device__ __forceinline__ float modpos(float x) {
    float r = fmodf(x, TWO_PI_F);
    if (r < 0.0f) r += TWO_PI_F;
    return r;
}
__device__ __forceinline__ unsigned fmono(float f) {
    unsigned u = __float_as_uint(f);
    return (u & 0x80000000u) ? ~u : (u | 0x80000000u);
}
__device__ __forceinline__ unsigned short f2bf(float f) {  // RNE f32->bf16 bits
    unsigned u = __float_as_uint(f);
    return (unsigned short)((u + 0x7FFFu + ((u >> 16) & 1u)) >> 16);
}
__device__ __forceinline__ float bf2f(unsigned short h) {
    return __uint_as_float(((unsigned)h) << 16);
}

// Fragment-major table layout: element (row, k) ->
//   (row>>5)*2048 + (k>>4)*512 + ((k>>3)&1)*256 + (row&31)*8 + (k&7)
// A wave's (group, ks) fragment is 1KB contiguous: base + lane*8 ushorts.
// Values PRE-SCALED by 1/norm so MFMA output is the final sim value.

// -------- phase encode + advance + norm-scaled bf16 hi/mid/lo planes --------
__global__ __launch_bounds__(128) void encode_kernel(
    const float* __restrict__ detA, const float* __restrict__ detB,
    const float* __restrict__ W1, const float* __restrict__ b1,
    const float* __restrict__ W2, const float* __restrict__ b2,
    const float* __restrict__ freq,
    unsigned short* __restrict__ tabA, unsigned short* __restrict__ tabB,
    unsigned long long* __restrict__ rowMax, unsigned long long* __restrict__ colWin)
{
    __shared__ float sW1[4 * 64];
    __shared__ float sb1[64];
    __shared__ float sW2[64 * N_OSC];
    __shared__ float sb2[N_OSC];
    __shared__ float sDelta[N_OSC];

    int t = threadIdx.x;
    for (int i = t; i < 4 * 64; i += 128) sW1[i] = W1[i];
    for (int i = t; i < 64; i += 128) sb1[i] = b1[i];
    for (int i = t; i < 64 * N_OSC; i += 128) sW2[i] = W2[i];
    for (int i = t; i < N_OSC; i += 128) {
        sb2[i] = b2[i];
        sDelta[i] = (TWO_PI_F * freq[i]) * 0.01f;
    }
    __syncthreads();

    int gid = blockIdx.x * 128 + t;      // 16384 total
    bool isA = gid < NR;
    int row = isA ? gid : gid - NR;
    const float* det = isA ? detA : detB;
    unsigned short* tab = isA ? tabA : tabB;

    // fold the two tiny memsets into this kernel
    if (isA) rowMax[gid] = 0ull; else colWin[gid - NR] = 0ull;

    float4 xv = *(const float4*)(det + (size_t)row * 4);
    float x0 = xv.x, x1 = xv.y, x2 = xv.z, x3 = xv.w;

    float h[64];
#pragma unroll
    for (int j = 0; j < 64; ++j) {
        float a = x0 * sW1[0 * 64 + j];
        a += x1 * sW1[1 * 64 + j];
        a += x2 * sW1[2 * 64 + j];
        a += x3 * sW1[3 * 64 + j];
        a += sb1[j];
        h[j] = fmaxf(a, 0.0f);
    }

    float raw[N_OSC];
#pragma unroll
    for (int o = 0; o < N_OSC; ++o) raw[o] = 0.0f;
#pragma unroll
    for (int j = 0; j < 64; ++j) {
        float hj = h[j];
#pragma unroll
        for (int o = 0; o < N_OSC; ++o) raw[o] += hj * sW2[j * N_OSC + o];
    }

    float cv[N_OSC], sv[N_OSC];
    float csum = 0.0f;
#pragma unroll
    for (int o = 0; o < N_OSC; ++o) {
        float p = raw[o] + sb2[o];
        p = modpos(p);
        if (isA) {
            float d = sDelta[o];
#pragma unroll
            for (int s = 0; s < 5; ++s) { p = modpos(p + d); }
        }
        float sn, cs;
        sincosf(p, &sn, &cs);
        cv[o] = cs; sv[o] = sn;
        csum += cs * cs + sn * sn;
    }
    float irn = 1.0f / (sqrtf(csum) + 1e-6f);

    unsigned h2[32], m2[32], l2[32];
#pragma unroll
    for (int i = 0; i < 32; ++i) { h2[i] = 0u; m2[i] = 0u; l2[i] = 0u; }

#pragma unroll
    for (int o = 0; o < N_OSC; ++o) {
        {   // k = o (cos, scaled)
            float x = cv[o] * irn;
            unsigned short v0 = f2bf(x); float r1 = x - bf2f(v0);
            unsigned short v1 = f2bf(r1); float r2 = r1 - bf2f(v1);
            unsigned short v2 = f2bf(r2);
            const int k = o, i = k >> 1, sh = (k & 1) * 16;
            h2[i] |= ((unsigned)v0) << sh;
            m2[i] |= ((unsigned)v1) << sh;
            l2[i] |= ((unsigned)v2) << sh;
        }
        {   // k = 28 + o (sin, scaled)
            float x = sv[o] * irn;
            unsigned short v0 = f2bf(x); float r1 = x - bf2f(v0);
            unsigned short v1 = f2bf(r1); float r2 = r1 - bf2f(v1);
            unsigned short v2 = f2bf(r2);
            const int k = 28 + o, i = k >> 1, sh = (k & 1) * 16;
            h2[i] |= ((unsigned)v0) << sh;
            m2[i] |= ((unsigned)v1) << sh;
            l2[i] |= ((unsigned)v2) << sh;
        }
    }

    size_t gbase = (size_t)(row >> 5) * 2048 + (size_t)(row & 31) * 8;
#pragma unroll
    for (int c = 0; c < 8; ++c) {
        size_t off = gbase + (size_t)(c >> 1) * 512 + (size_t)(c & 1) * 256;
        u32x4 vh, vm, vl;
#pragma unroll
        for (int e = 0; e < 4; ++e) {
            vh[e] = h2[c * 4 + e]; vm[e] = m2[c * 4 + e]; vl[e] = l2[c * 4 + e];
        }
        *(u32x4*)(tab + off) = vh;
        *(u32x4*)(tab + PLANE + off) = vm;
        *(u32x4*)(tab + 2 * PLANE + off) = vl;
    }
}

#define MFMA(a, b, c) __builtin_amdgcn_mfma_f32_32x32x16_bf16((a), (b), (c), 0, 0, 0)

// -------- sim: 128x128 tile, 4-wave quadrants, conflict-free LDS staging,
//          swapped-operand MFMA, in-register row-max, b128 scratch epilogue.
//          NO sched_barrier pins (m141: they defeat compiler scheduling). --------
__global__ __launch_bounds__(256) void sim_kernel(
    const unsigned short* __restrict__ tabA, const unsigned short* __restrict__ tabB,
    float* __restrict__ simOut, unsigned long long* __restrict__ rowMax)
{
    __shared__ __align__(16) unsigned char smem[81920];
    // [0,49152): B 3 planes x 4 groups x 4 ks x 1KB
    // [49152, 81920): A double buffer, 2 x (4 groups x 4 ks x 1KB)
    // epilogue: reused as 4 x 16640B wave-private scratch

    int bid = blockIdx.x;
    int swz = (bid & 7) * 512 + (bid >> 3);    // 4096 blocks, bijective XCD swizzle
    int bx = swz & 63, by = swz >> 6;
    int r0 = by * 128, c0 = bx * 128;

    int t = threadIdx.x, w = t >> 6, l = t & 63;
    int wr = w >> 1, wc = w & 1;
    int l31 = l & 31, h5 = l >> 5;
    int gA0 = r0 >> 5, gB0 = c0 >> 5;
    size_t l8 = (size_t)l * 8;

    // ---- stage B (48 units) + A_hi (16 units) ----
#pragma unroll
    for (int i = 0; i < 12; ++i) {
        int unit = w * 12 + i;
        int p = unit >> 4, rem = unit & 15;
        int g = rem >> 2, ks = rem & 3;
        const unsigned short* src = tabB + (size_t)p * PLANE
            + (size_t)(gB0 + g) * 2048 + (size_t)ks * 512 + l8;
        __builtin_amdgcn_global_load_lds(AS1C(src), AS3(smem + unit * 1024), 16, 0, 0);
    }
#pragma unroll
    for (int i = 0; i < 4; ++i) {
        int unit = w * 4 + i;
        int g = unit >> 2, ks = unit & 3;
        const unsigned short* src = tabA
            + (size_t)(gA0 + g) * 2048 + (size_t)ks * 512 + l8;
        __builtin_amdgcn_global_load_lds(AS1C(src), AS3(smem + 49152 + unit * 1024), 16, 0, 0);
    }
    __syncthreads();

    // issue A_mid into buf1 (fresh region; lands by next barrier)
#pragma unroll
    for (int i = 0; i < 4; ++i) {
        int unit = w * 4 + i;
        int g = unit >> 2, ks = unit & 3;
        const unsigned short* src = tabA + PLANE
            + (size_t)(gA0 + g) * 2048 + (size_t)ks * 512 + l8;
        __builtin_amdgcn_global_load_lds(AS1C(src), AS3(smem + 65536 + unit * 1024), 16, 0, 0);
    }

    f32x16 acc00, acc01, acc10, acc11;   // acc[ag][bg]
#pragma unroll
    for (int r = 0; r < 16; ++r) { acc00[r] = 0.f; acc01[r] = 0.f; acc10[r] = 0.f; acc11[r] = 0.f; }

#define LDB(p, gg, ks) (*(const s16x8*)(smem + (((p) * 16 + (2 * wc + (gg)) * 4 + (ks)) * 1024) + (size_t)l * 16))
#define LDA(buf, gg, ks) (*(const s16x8*)(smem + 49152 + (buf) * 16384 + (((2 * wr + (gg)) * 4 + (ks)) * 1024) + (size_t)l * 16))

    s16x8 bh0[4], bh1[4];    // B_hi cached across phases (32 VGPR)

    // phase 0: A_hi x {B_hi, B_mid, B_lo}
#pragma unroll
    for (int ks = 0; ks < 4; ++ks) {
        s16x8 ah0 = LDA(0, 0, ks), ah1 = LDA(0, 1, ks);
        bh0[ks] = LDB(0, 0, ks); bh1[ks] = LDB(0, 1, ks);
        s16x8 q0 = LDB(1, 0, ks), q1 = LDB(1, 1, ks);
        s16x8 p0 = LDB(2, 0, ks), p1 = LDB(2, 1, ks);
        acc00 = MFMA(bh0[ks], ah0, acc00); acc01 = MFMA(bh1[ks], ah0, acc01);   // hh
        acc10 = MFMA(bh0[ks], ah1, acc10); acc11 = MFMA(bh1[ks], ah1, acc11);
        acc00 = MFMA(q0, ah0, acc00); acc01 = MFMA(q1, ah0, acc01);             // hm
        acc10 = MFMA(q0, ah1, acc10); acc11 = MFMA(q1, ah1, acc11);
        acc00 = MFMA(p0, ah0, acc00); acc01 = MFMA(p1, ah0, acc01);             // hl
        acc10 = MFMA(p0, ah1, acc10); acc11 = MFMA(p1, ah1, acc11);
    }
    __syncthreads();

    // issue A_lo into buf0 (A_hi fully consumed)
#pragma unroll
    for (int i = 0; i < 4; ++i) {
        int unit = w * 4 + i;
        int g = unit >> 2, ks = unit & 3;
        const unsigned short* src = tabA + 2 * PLANE
            + (size_t)(gA0 + g) * 2048 + (size_t)ks * 512 + l8;
        __builtin_amdgcn_global_load_lds(AS1C(src), AS3(smem + 49152 + unit * 1024), 16, 0, 0);
    }

    // phase 1: A_mid x {B_hi(regs), B_mid}
#pragma unroll
    for (int ks = 0; ks < 4; ++ks) {
        s16x8 am0 = LDA(1, 0, ks), am1 = LDA(1, 1, ks);
        s16x8 q0 = LDB(1, 0, ks), q1 = LDB(1, 1, ks);
        acc00 = MFMA(bh0[ks], am0, acc00); acc01 = MFMA(bh1[ks], am0, acc01);   // mh
        acc10 = MFMA(bh0[ks], am1, acc10); acc11 = MFMA(bh1[ks], am1, acc11);
        acc00 = MFMA(q0, am0, acc00); acc01 = MFMA(q1, am0, acc01);             // mm
        acc10 = MFMA(q0, am1, acc10); acc11 = MFMA(q1, am1, acc11);
    }
    __syncthreads();

    // phase 2: A_lo x B_hi(regs)
#pragma unroll
    for (int ks = 0; ks < 4; ++ks) {
        s16x8 al0 = LDA(0, 0, ks), al1 = LDA(0, 1, ks);
        acc00 = MFMA(bh0[ks], al0, acc00); acc01 = MFMA(bh1[ks], al0, acc01);   // lh
        acc10 = MFMA(bh0[ks], al1, acc10); acc11 = MFMA(bh1[ks], al1, acc11);
    }
#undef LDA
#undef LDB

    // ---- in-register row max/argmax (rows lane-local via swapped operands) ----
    int cbase = c0 + wc * 64 + 4 * h5;
    unsigned long long key0 = 0ull, key1 = 0ull;
#pragma unroll
    for (int r = 0; r < 16; ++r) {
        int pa = (r & 3) + 8 * (r >> 2);
        unsigned col0 = (unsigned)(cbase + pa);
        unsigned col1 = (unsigned)(cbase + 32 + pa);
        unsigned long long k;
        k = ((unsigned long long)fmono(acc00[r]) << 32) | (unsigned long long)(0xFFFFFFFFu - col0);
        if (k > key0) key0 = k;
        k = ((unsigned long long)fmono(acc01[r]) << 32) | (unsigned long long)(0xFFFFFFFFu - col1);
        if (k > key0) key0 = k;
        k = ((unsigned long long)fmono(acc10[r]) << 32) | (unsigned long long)(0xFFFFFFFFu - col0);
        if (k > key1) key1 = k;
        k = ((unsigned long long)fmono(acc11[r]) << 32) | (unsigned long long)(0xFFFFFFFFu - col1);
        if (k > key1) key1 = k;
    }
    {   // merge lane l <-> l+32 (same rows, complementary col subsets)
        unsigned lo = (unsigned)key0, hi = (unsigned)(key0 >> 32);
        unsigned olo = __shfl_xor(lo, 32, 64), ohi = __shfl_xor(hi, 32, 64);
        unsigned long long o = ((unsigned long long)ohi << 32) | olo;
        if (o > key0) key0 = o;
        lo = (unsigned)key1; hi = (unsigned)(key1 >> 32);
        olo = __shfl_xor(lo, 32, 64); ohi = __shfl_xor(hi, 32, 64);
        o = ((unsigned long long)ohi << 32) | olo;
        if (o > key1) key1 = o;
    }
    if (l < 32) {
        atomicMax(&rowMax[r0 + wr * 64 + l], key0);
        atomicMax(&rowMax[r0 + wr * 64 + 32 + l], key1);
    }

    // ---- store via wave-private LDS transpose scratch (b128 both ways) ----
    __syncthreads();                          // all LDS reads done; reuse smem
    float* scr = (float*)(smem + w * 16640);  // 64 rows x pitch 65 floats

#pragma unroll
    for (int ag = 0; ag < 2; ++ag) {
#pragma unroll
        for (int bg = 0; bg < 2; ++bg) {
#pragma unroll
            for (int k = 0; k < 4; ++k) {
                f32x4 v;
#pragma unroll
                for (int e = 0; e < 4; ++e) {
                    float x = ag == 0 ? (bg == 0 ? acc00[4 * k + e] : acc01[4 * k + e])
                                      : (bg == 0 ? acc10[4 * k + e] : acc11[4 * k + e]);
                    v[e] = x;
                }
                int rrow = ag * 32 + l31;
                int ccol = bg * 32 + 8 * k + 4 * h5;
                *(f32x4*)&scr[rrow * 65 + ccol] = v;
            }
        }
    }
    // wave-private: no barrier between write and read

#pragma unroll
    for (int s = 0; s < 16; ++s) {
        int lr = 4 * s + (l >> 4);
        f32x4 v = *(const f32x4*)&scr[lr * 65 + (l & 15) * 4];
        __builtin_nontemporal_store(v,
            (f32x4*)&simOut[(size_t)(r0 + wr * 64 + lr) * NR + c0 + wc * 64 + (l & 15) * 4]);
    }
}

// -------- per-row: init matches, claim column --------
__global__ __launch_bounds__(256) void rowwin_kernel(
    const unsigned long long* __restrict__ rowMax,
    unsigned long long* __restrict__ colWin,
    float* __restrict__ outMatches)
{
    int r = blockIdx.x * 256 + threadIdx.x;
    if (r >= NR) return;
    outMatches[r] = -1.0f;
    unsigned long long key = rowMax[r];
    unsigned m = (unsigned)(key >> 32);
    unsigned bits = (m & 0x80000000u) ? (m ^ 0x80000000u) : ~m;
    float ms = __uint_as_float(bits);
    unsigned col = 0xFFFFFFFFu - (unsigned)key;
    if (ms > 0.3f) {
        unsigned long long ck = ((unsigned long long)m << 32)
                              | (unsigned long long)(0xFFFFFFFFu - (unsigned)r);
        atomicMax(&colWin[col], ck);
    }
}

// -------- per-column: winner takes the column --------
__global__ __launch_bounds__(256) void colfin_kernel(
    const unsigned long long* __restrict__ colWin,
    float* __restrict__ outMatches)
{
    int j = blockIdx.x * 256 + threadIdx.x;
    if (j >= NR) return;
    unsigned long long w = colWin[j];
    if (w != 0ull) {
        unsigned r = 0xFFFFFFFFu - (unsigned)w;
        outMatches[r] = (float)j;
    }
}

extern "C" void kernel_launch(void* const* d_in, const int* in_sizes, int n_in,
                              void* d_out, int out_size, void* d_ws, size_t ws_size,
                              hipStream_t stream) {
    const float* detA = (const float*)d_in[0];
    const float* detB = (const float*)d_in[1];
    const float* W1   = (const float*)d_in[2];
    const float* b1   = (const float*)d_in[3];
    const float* W2   = (const float*)d_in[4];
    const float* b2   = (const float*)d_in[5];
    const float* freq = (const float*)d_in[6];
    float* out = (float*)d_out;

    char* ws = (char*)d_ws;
    unsigned short* tabA = (unsigned short*)(ws);             // 3 planes x 1 MB
    unsigned short* tabB = (unsigned short*)(ws + 3145728);   // 3 planes x 1 MB
    unsigned long long* rowMax = (unsigned long long*)(ws + 6291456); // 64 KB
    unsigned long long* colWin = (unsigned long long*)(ws + 6356992); // 64 KB

    encode_kernel<<<128, 128, 0, stream>>>(detA, detB, W1, b1, W2, b2, freq,
                                           tabA, tabB, rowMax, colWin);
    sim_kernel<<<4096, 256, 0, stream>>>(tabA, tabB, out + NR, rowMax);
    rowwin_kernel<<<NR / 256, 256, 0, stream>>>(rowMax, colWin, out);
    colfin_kernel<<<NR / 256, 256, 0, stream>>>(colWin, out);
}

// Round 18
// 125.789 us; speedup vs baseline: 1.2797x; 1.2697x over previous
//
#include <hip/hip_runtime.h>
#include <math.h>

#define NR 8192
#define N_OSC 28
#define TWO_PI_F 6.28318530717958647692f
#define PLANE 524288   // 8192 rows * 64 k, ushorts, per plane

typedef __attribute__((ext_vector_type(8))) short s16x8;
typedef __attribute__((ext_vector_type(16))) float f32x16;
typedef __attribute__((ext_vector_type(4))) float f32x4;

#define AS3(p) ((__attribute__((address_space(3))) void*)(p))
#define AS1C(p) ((const __attribute__((address_space(1))) void*)(p))

__device__ __forceinline__ float modpos(float x) {
    float r = fmodf(x, TWO_PI_F);
    if (r < 0.0f) r += TWO_PI_F;
    return r;
}
__device__ __forceinline__ unsigned fmono(float f) {
    unsigned u = __float_as_uint(f);
    return (u & 0x80000000u) ? ~u : (u | 0x80000000u);
}
__device__ __forceinline__ unsigned short f2bf(float f) {  // RNE f32->bf16 bits
    unsigned u = __float_as_uint(f);
    return (unsigned short)((u + 0x7FFFu + ((u >> 16) & 1u)) >> 16);
}
__device__ __forceinline__ float bf2f(unsigned short h) {
    return __uint_as_float(((unsigned)h) << 16);
}

// -------- phase encode + advance + bf16 hi/mid/lo planes + reciprocal norm --------
__global__ __launch_bounds__(256) void encode_kernel(
    const float* __restrict__ detA, const float* __restrict__ detB,
    const float* __restrict__ W1, const float* __restrict__ b1,
    const float* __restrict__ W2, const float* __restrict__ b2,
    const float* __restrict__ freq,
    unsigned short* __restrict__ tabA, unsigned short* __restrict__ tabB,
    float* __restrict__ normA, float* __restrict__ normB,
    unsigned long long* __restrict__ rowMax, unsigned long long* __restrict__ colWin)
{
    __shared__ float sW1[4 * 64];
    __shared__ float sb1[64];
    __shared__ float sW2[64 * N_OSC];
    __shared__ float sb2[N_OSC];
    __shared__ float sDelta[N_OSC];

    int t = threadIdx.x;
    for (int i = t; i < 4 * 64; i += 256) sW1[i] = W1[i];
    for (int i = t; i < 64; i += 256) sb1[i] = b1[i];
    for (int i = t; i < 64 * N_OSC; i += 256) sW2[i] = W2[i];
    for (int i = t; i < N_OSC; i += 256) {
        sb2[i] = b2[i];
        sDelta[i] = (TWO_PI_F * freq[i]) * 0.01f;
    }
    __syncthreads();

    int gid = blockIdx.x * 256 + t;
    bool isA = gid < NR;
    int row = isA ? gid : gid - NR;
    const float* det = isA ? detA : detB;
    unsigned short* tab = isA ? tabA : tabB;
    float* nrm = isA ? normA : normB;

    // fold the two tiny memsets into this kernel (16384 threads == NR*2)
    if (isA) rowMax[gid] = 0ull; else colWin[gid - NR] = 0ull;

    float4 xv = *(const float4*)(det + (size_t)row * 4);
    float x0 = xv.x, x1 = xv.y, x2 = xv.z, x3 = xv.w;

    float h[64];
#pragma unroll
    for (int j = 0; j < 64; ++j) {
        float a = x0 * sW1[0 * 64 + j];
        a += x1 * sW1[1 * 64 + j];
        a += x2 * sW1[2 * 64 + j];
        a += x3 * sW1[3 * 64 + j];
        a += sb1[j];
        h[j] = fmaxf(a, 0.0f);
    }

    float raw[N_OSC];
#pragma unroll
    for (int o = 0; o < N_OSC; ++o) raw[o] = 0.0f;
#pragma unroll
    for (int j = 0; j < 64; ++j) {
        float hj = h[j];
#pragma unroll
        for (int o = 0; o < N_OSC; ++o) raw[o] += hj * sW2[j * N_OSC + o];
    }

    int rs = row & 7;               // chunk-XOR swizzle key
    size_t rbase = (size_t)row * 64;
    float csum = 0.0f;
#pragma unroll
    for (int o = 0; o < N_OSC; ++o) {
        float p = raw[o] + sb2[o];
        p = modpos(p);
        if (isA) {
            float d = sDelta[o];
#pragma unroll
            for (int s = 0; s < 5; ++s) { p = modpos(p + d); }
        }
        float sn, cs;
        sincosf(p, &sn, &cs);
        csum += cs * cs + sn * sn;
        {
            int k = o;
            unsigned short h0 = f2bf(cs); float r1 = cs - bf2f(h0);
            unsigned short h1 = f2bf(r1); float r2 = r1 - bf2f(h1);
            unsigned short h2 = f2bf(r2);
            size_t e = rbase + ((((k >> 3) ^ rs) << 3) | (k & 7));
            tab[e] = h0; tab[PLANE + e] = h1; tab[2 * PLANE + e] = h2;
        }
        {
            int k = 28 + o;
            unsigned short h0 = f2bf(sn); float r1 = sn - bf2f(h0);
            unsigned short h1 = f2bf(r1); float r2 = r1 - bf2f(h1);
            unsigned short h2 = f2bf(r2);
            size_t e = rbase + ((((k >> 3) ^ rs) << 3) | (k & 7));
            tab[e] = h0; tab[PLANE + e] = h1; tab[2 * PLANE + e] = h2;
        }
    }
#pragma unroll
    for (int k = 56; k < 64; ++k) {
        size_t e = rbase + ((((k >> 3) ^ rs) << 3) | (k & 7));
        tab[e] = 0; tab[PLANE + e] = 0; tab[2 * PLANE + e] = 0;
    }
    nrm[row] = 1.0f / (sqrtf(csum) + 1e-6f);    // reciprocal norm
}

__device__ __forceinline__ void stage_plane(const unsigned short* __restrict__ tab,
                                            int dim0, unsigned short* dst,
                                            int w, int l)
{
#pragma unroll
    for (int i = 0; i < 4; ++i) {
        int u = w * 4 + i;
        const unsigned short* g = tab + (size_t)(dim0 + 8 * u + (l >> 3)) * 64 + (l & 7) * 8;
        __builtin_amdgcn_global_load_lds(AS1C(g), AS3(dst + u * 512), 16, 0, 0);
    }
}

// -------- sim via bf16-split MFMA; LDS-scratch epilogue (no shuffle butterflies) --------
__global__ __launch_bounds__(256) void sim_kernel(
    const unsigned short* __restrict__ tabA, const unsigned short* __restrict__ tabB,
    const float* __restrict__ normA, const float* __restrict__ normB,
    float* __restrict__ simOut, unsigned long long* __restrict__ rowMax)
{
    __shared__ __align__(16) unsigned char smem[81920];
    unsigned short* Bsh0 = (unsigned short*)(smem);
    unsigned short* Bsh1 = (unsigned short*)(smem + 16384);
    unsigned short* Bsh2 = (unsigned short*)(smem + 32768);
    unsigned short* Ash0 = (unsigned short*)(smem + 49152);
    unsigned short* Ash1 = (unsigned short*)(smem + 65536);

    int bid = blockIdx.x;
    int swz = (bid & 7) * 512 + (bid >> 3);
    int bx = swz & 63, by = swz >> 6;
    int r0 = by * 128, c0 = bx * 128;

    int t = threadIdx.x, w = t >> 6, l = t & 63;
    int wr = w >> 1, wc = w & 1;
    int lrow = l & 31;
    int kh2 = (l >> 5) * 16;
    int sw = (lrow & 7) << 4;

    stage_plane(tabB, c0, Bsh0, w, l);
    stage_plane(tabB + PLANE, c0, Bsh1, w, l);
    stage_plane(tabB + 2 * PLANE, c0, Bsh2, w, l);
    stage_plane(tabA, r0, Ash0, w, l);
    __syncthreads();
    stage_plane(tabA + PLANE, r0, Ash1, w, l);   // A_mid in flight during phase 0

    f32x16 acc00, acc01, acc10, acc11;
#pragma unroll
    for (int r = 0; r < 16; ++r) { acc00[r] = 0.f; acc01[r] = 0.f; acc10[r] = 0.f; acc11[r] = 0.f; }

    int baA0 = (wr * 64 + lrow) * 128, baA1 = baA0 + 32 * 128;
    int baB0 = (wc * 64 + lrow) * 128, baB1 = baB0 + 32 * 128;

#define FR(arr, ba, ks) (*(const s16x8*)((const char*)(arr) + (ba) + (((ks) * 32 + kh2) ^ sw)))

    s16x8 bh0[4], bh1[4];   // B_hi fragments cached across all 3 phases (32 VGPR)

    // phase 0: A_hi x {B_hi, B_mid, B_lo}
#pragma unroll
    for (int ks = 0; ks < 4; ++ks) {
        s16x8 a0 = FR(Ash0, baA0, ks), a1 = FR(Ash0, baA1, ks);
        bh0[ks] = FR(Bsh0, baB0, ks); bh1[ks] = FR(Bsh0, baB1, ks);
        acc00 = __builtin_amdgcn_mfma_f32_32x32x16_bf16(a0, bh0[ks], acc00, 0, 0, 0);
        acc01 = __builtin_amdgcn_mfma_f32_32x32x16_bf16(a0, bh1[ks], acc01, 0, 0, 0);
        acc10 = __builtin_amdgcn_mfma_f32_32x32x16_bf16(a1, bh0[ks], acc10, 0, 0, 0);
        acc11 = __builtin_amdgcn_mfma_f32_32x32x16_bf16(a1, bh1[ks], acc11, 0, 0, 0);
        s16x8 b0 = FR(Bsh1, baB0, ks), b1 = FR(Bsh1, baB1, ks);
        acc00 = __builtin_amdgcn_mfma_f32_32x32x16_bf16(a0, b0, acc00, 0, 0, 0);
        acc01 = __builtin_amdgcn_mfma_f32_32x32x16_bf16(a0, b1, acc01, 0, 0, 0);
        acc10 = __builtin_amdgcn_mfma_f32_32x32x16_bf16(a1, b0, acc10, 0, 0, 0);
        acc11 = __builtin_amdgcn_mfma_f32_32x32x16_bf16(a1, b1, acc11, 0, 0, 0);
        b0 = FR(Bsh2, baB0, ks); b1 = FR(Bsh2, baB1, ks);
        acc00 = __builtin_amdgcn_mfma_f32_32x32x16_bf16(a0, b0, acc00, 0, 0, 0);
        acc01 = __builtin_amdgcn_mfma_f32_32x32x16_bf16(a0, b1, acc01, 0, 0, 0);
        acc10 = __builtin_amdgcn_mfma_f32_32x32x16_bf16(a1, b0, acc10, 0, 0, 0);
        acc11 = __builtin_amdgcn_mfma_f32_32x32x16_bf16(a1, b1, acc11, 0, 0, 0);
    }
    __syncthreads();
    stage_plane(tabA + 2 * PLANE, r0, Ash0, w, l);   // A_lo in flight during phase 1

    // phase 1: A_mid x {B_hi(regs), B_mid}
#pragma unroll
    for (int ks = 0; ks < 4; ++ks) {
        s16x8 a0 = FR(Ash1, baA0, ks), a1 = FR(Ash1, baA1, ks);
        acc00 = __builtin_amdgcn_mfma_f32_32x32x16_bf16(a0, bh0[ks], acc00, 0, 0, 0);
        acc01 = __builtin_amdgcn_mfma_f32_32x32x16_bf16(a0, bh1[ks], acc01, 0, 0, 0);
        acc10 = __builtin_amdgcn_mfma_f32_32x32x16_bf16(a1, bh0[ks], acc10, 0, 0, 0);
        acc11 = __builtin_amdgcn_mfma_f32_32x32x16_bf16(a1, bh1[ks], acc11, 0, 0, 0);
        s16x8 b0 = FR(Bsh1, baB0, ks), b1 = FR(Bsh1, baB1, ks);
        acc00 = __builtin_amdgcn_mfma_f32_32x32x16_bf16(a0, b0, acc00, 0, 0, 0);
        acc01 = __builtin_amdgcn_mfma_f32_32x32x16_bf16(a0, b1, acc01, 0, 0, 0);
        acc10 = __builtin_amdgcn_mfma_f32_32x32x16_bf16(a1, b0, acc10, 0, 0, 0);
        acc11 = __builtin_amdgcn_mfma_f32_32x32x16_bf16(a1, b1, acc11, 0, 0, 0);
    }
    __syncthreads();

    // phase 2: A_lo x B_hi(regs)
#pragma unroll
    for (int ks = 0; ks < 4; ++ks) {
        s16x8 a0 = FR(Ash0, baA0, ks), a1 = FR(Ash0, baA1, ks);
        acc00 = __builtin_amdgcn_mfma_f32_32x32x16_bf16(a0, bh0[ks], acc00, 0, 0, 0);
        acc01 = __builtin_amdgcn_mfma_f32_32x32x16_bf16(a0, bh1[ks], acc01, 0, 0, 0);
        acc10 = __builtin_amdgcn_mfma_f32_32x32x16_bf16(a1, bh0[ks], acc10, 0, 0, 0);
        acc11 = __builtin_amdgcn_mfma_f32_32x32x16_bf16(a1, bh1[ks], acc11, 0, 0, 0);
    }
#undef FR

    float icn0 = normB[c0 + wc * 64 + lrow];        // reciprocal norms
    float icn1 = normB[c0 + wc * 64 + 32 + lrow];

    __syncthreads();                                 // staging LDS -> scratch reuse
    float* scr = (float*)(smem + w * 17408);         // 64 rows x pitch 68 floats

#pragma unroll
    for (int r = 0; r < 16; ++r) {
        int rd0 = (r & 3) + 8 * (r >> 2) + 4 * (l >> 5);
        float irn0 = normA[r0 + wr * 64 + rd0];
        scr[rd0 * 68 + lrow]      = acc00[r] * (irn0 * icn0);
        scr[rd0 * 68 + 32 + lrow] = acc01[r] * (irn0 * icn1);
        int rd1 = rd0 + 32;
        float irn1 = normA[r0 + wr * 64 + rd1];
        scr[rd1 * 68 + lrow]      = acc10[r] * (irn1 * icn0);
        scr[rd1 * 68 + 32 + lrow] = acc11[r] * (irn1 * icn1);
    }
    // wave-private scratch: no barrier needed between write and read

    // coalesced NT stores: 16 insts x 1KB
#pragma unroll
    for (int s = 0; s < 16; ++s) {
        int lr = 4 * s + (l >> 4);
        f32x4 v = *(const f32x4*)&scr[lr * 68 + (l & 15) * 4];
        int grow = r0 + wr * 64 + lr;
        __builtin_nontemporal_store(v,
            (f32x4*)&simOut[(size_t)grow * NR + c0 + wc * 64 + (l & 15) * 4]);
    }

    // per-lane row max: lane l owns row l of the wave tile (pure VALU scan)
    {
        const float* rp = &scr[l * 68];
        float mv = -2.0f; int mc = 0;
#pragma unroll
        for (int c4 = 0; c4 < 16; ++c4) {
            f32x4 v = *(const f32x4*)&rp[c4 * 4];
#pragma unroll
            for (int e = 0; e < 4; ++e) {
                bool g = v[e] > mv;
                mv = g ? v[e] : mv;
                mc = g ? c4 * 4 + e : mc;
            }
        }
        int grow = r0 + wr * 64 + l;
        unsigned gcol = (unsigned)(c0 + wc * 64 + mc);
        unsigned long long key = ((unsigned long long)fmono(mv) << 32)
                               | (unsigned long long)(0xFFFFFFFFu - gcol);
        atomicMax(&rowMax[grow], key);
    }
}

// -------- per-row: init matches, claim column --------
__global__ __launch_bounds__(256) void rowwin_kernel(
    const unsigned long long* __restrict__ rowMax,
    unsigned long long* __restrict__ colWin,
    float* __restrict__ outMatches)
{
    int r = blockIdx.x * 256 + threadIdx.x;
    if (r >= NR) return;
    outMatches[r] = -1.0f;
    unsigned long long key = rowMax[r];
    unsigned m = (unsigned)(key >> 32);
    unsigned bits = (m & 0x80000000u) ? (m ^ 0x80000000u) : ~m;
    float ms = __uint_as_float(bits);
    unsigned col = 0xFFFFFFFFu - (unsigned)key;
    if (ms > 0.3f) {
        unsigned long long ck = ((unsigned long long)m << 32)
                              | (unsigned long long)(0xFFFFFFFFu - (unsigned)r);
        atomicMax(&colWin[col], ck);
    }
}

// -------- per-column: winner takes the column --------
__global__ __launch_bounds__(256) void colfin_kernel(
    const unsigned long long* __restrict__ colWin,
    float* __restrict__ outMatches)
{
    int j = blockIdx.x * 256 + threadIdx.x;
    if (j >= NR) return;
    unsigned long long w = colWin[j];
    if (w != 0ull) {
        unsigned r = 0xFFFFFFFFu - (unsigned)w;
        outMatches[r] = (float)j;
    }
}

extern "C" void kernel_launch(void* const* d_in, const int* in_sizes, int n_in,
                              void* d_out, int out_size, void* d_ws, size_t ws_size,
                              hipStream_t stream) {
    const float* detA = (const float*)d_in[0];
    const float* detB = (const float*)d_in[1];
    const float* W1   = (const float*)d_in[2];
    const float* b1   = (const float*)d_in[3];
    const float* W2   = (const float*)d_in[4];
    const float* b2   = (const float*)d_in[5];
    const float* freq = (const float*)d_in[6];
    float* out = (float*)d_out;

    char* ws = (char*)d_ws;
    unsigned short* tabA = (unsigned short*)(ws);             // 3 planes x 1 MB
    unsigned short* tabB = (unsigned short*)(ws + 3145728);   // 3 planes x 1 MB
    float* normA = (float*)(ws + 6291456);
    float* normB = (float*)(ws + 6324224);
    unsigned long long* rowMax = (unsigned long long*)(ws + 6356992);
    unsigned long long* colWin = (unsigned long long*)(ws + 6422528);

    encode_kernel<<<64, 256, 0, stream>>>(detA, detB, W1, b1, W2, b2, freq,
                                          tabA, tabB, normA, normB, rowMax, colWin);
    sim_kernel<<<4096, 256, 0, stream>>>(tabA, tabB, normA, normB, out + NR, rowMax);
    rowwin_kernel<<<NR / 256, 256, 0, stream>>>(rowMax, colWin, out);
    colfin_kernel<<<NR / 256, 256, 0, stream>>>(colWin, out);
}